// Round 10
// baseline (502.994 us; speedup 1.0000x reference)
//
#include <hip/hip_runtime.h>

#define NSLOPE 0.2f
#define GEPS 1e-5f

typedef unsigned short ushortT;
typedef __attribute__((ext_vector_type(8))) unsigned short us8;
typedef __attribute__((ext_vector_type(8))) __bf16 bf16x8;
typedef __attribute__((ext_vector_type(4))) float f32x4;

__device__ __forceinline__ float lrelu(float x) { return x >= 0.f ? x : NSLOPE * x; }
__device__ __forceinline__ ushortT f2bf(float f) {
    unsigned int u = __float_as_uint(f);
    return (ushortT)((u + 0x7fffu + ((u >> 16) & 1u)) >> 16);
}
__device__ __forceinline__ float bf2f(ushortT h) {
    return __uint_as_float((unsigned int)h << 16);
}

// ---------------- L0: weight prep (blocks 0..127)  ||  edge histogram (rest) ----------------
__global__ __launch_bounds__(256) void k_prep_hist(
    const float* __restrict__ w1, const float* __restrict__ w2,
    const float* __restrict__ g1w, const float* __restrict__ g2w,
    ushortT* __restrict__ w1t, ushortT* __restrict__ w2t,
    ushortT* __restrict__ g1t, ushortT* __restrict__ g2t,
    const int* __restrict__ dst, int* __restrict__ deg, int E)
{
    if (blockIdx.x >= 128) {
        const int i = (blockIdx.x - 128) * 256 + threadIdx.x;
        if (i < E) atomicAdd(&deg[dst[i]], 1);
        return;
    }
    const int i = blockIdx.x * 256 + threadIdx.x;
    if (i < 128 * 256) { const int c = i >> 8, k = i & 255; w1t[i] = f2bf(w1[k * 128 + c]); }
    if (i < 64 * 128)  { const int c = i >> 7, k = i & 127; w2t[i] = f2bf(w2[k * 64 + c]); }
    if (i < 256 * 64)  { const int c = i >> 6, k = i & 63;  g1t[i] = f2bf(g1w[k * 256 + c]); }
    if (i < 32 * 256)  { const int c = i >> 8, k = i & 255; g2t[i] = f2bf(g2w[k * 32 + c]); }
}

// ---------------- L1: MFMA GEMM 1 (blocks < gemmB)  ||  scan1 (rest) ----------------
__global__ __launch_bounds__(256) void k_lin1(const float* __restrict__ x,
    const ushortT* __restrict__ w1t, const float* __restrict__ b1,
    ushortT* __restrict__ h1, int n,
    const int* __restrict__ deg, int* __restrict__ offs, int* __restrict__ bsum, int gemmB)
{
    if ((int)blockIdx.x >= gemmB) {
        __shared__ int sm[256];
        const int t = threadIdx.x;
        const int i = (blockIdx.x - gemmB) * 256 + t;
        const int v = (i < n) ? deg[i] : 0;
        sm[t] = v;
        __syncthreads();
        for (int off = 1; off < 256; off <<= 1) {
            int add = (t >= off) ? sm[t - off] : 0;
            __syncthreads();
            sm[t] += add;
            __syncthreads();
        }
        if (i < n) offs[i] = sm[t] - v;
        if (t == 255) bsum[blockIdx.x - gemmB] = sm[255];
        return;
    }
    __shared__ us8 Ab[64 * 128 / 16];
    __shared__ us8 Bb[128 * 128 / 16];
    char* A = (char*)Ab; char* B = (char*)Bb;
    const int t = threadIdx.x;
    const int w = t >> 6, l = t & 63;
    const int lo = l & 15, hi = l >> 4;
    const int n0 = blockIdx.x * 64;
    const int wm = (w >> 1) * 32, wn = (w & 1) * 64;
    f32x4 acc[2][4];
    #pragma unroll
    for (int mf = 0; mf < 2; ++mf)
        #pragma unroll
        for (int nf = 0; nf < 4; ++nf) acc[mf][nf] = (f32x4){0.f, 0.f, 0.f, 0.f};

    const int arow = t >> 2, ak0 = (t & 3) * 16;
    int agn = n0 + arow; if (agn >= n) agn = n - 1;
    const int asw = (arow & 7) << 4;

    for (int kc = 0; kc < 4; ++kc) {
        __syncthreads();
        {
            ushortT tmp[16];
            const float* xp = &x[(size_t)agn * 256 + kc * 64 + ak0];
            #pragma unroll
            for (int j = 0; j < 4; ++j) {
                const float4 v = *(const float4*)(xp + j * 4);
                tmp[j*4+0] = f2bf(v.x); tmp[j*4+1] = f2bf(v.y);
                tmp[j*4+2] = f2bf(v.z); tmp[j*4+3] = f2bf(v.w);
            }
            *(us8*)(A + arow * 128 + ((ak0 * 2) ^ asw)) = *(us8*)tmp;
            *(us8*)(A + arow * 128 + ((ak0 * 2 + 16) ^ asw)) = *(us8*)(tmp + 8);
        }
        #pragma unroll
        for (int i = 0; i < 4; ++i) {
            const int idx = i * 256 + t, br = idx >> 3, bs = idx & 7;
            const us8 v = *(const us8*)&w1t[(size_t)br * 256 + kc * 64 + bs * 8];
            *(us8*)(B + br * 128 + ((bs * 16) ^ ((br & 7) << 4))) = v;
        }
        __syncthreads();
        #pragma unroll
        for (int ks = 0; ks < 2; ++ks) {
            const int koff = ks * 64 + hi * 16;
            bf16x8 af[2], bf[4];
            #pragma unroll
            for (int mf = 0; mf < 2; ++mf) {
                const int r = wm + mf * 16 + lo;
                af[mf] = *(const bf16x8*)(A + r * 128 + (koff ^ ((r & 7) << 4)));
            }
            #pragma unroll
            for (int nf = 0; nf < 4; ++nf) {
                const int r = wn + nf * 16 + lo;
                bf[nf] = *(const bf16x8*)(B + r * 128 + (koff ^ ((r & 7) << 4)));
            }
            #pragma unroll
            for (int mf = 0; mf < 2; ++mf)
                #pragma unroll
                for (int nf = 0; nf < 4; ++nf)
                    acc[mf][nf] = __builtin_amdgcn_mfma_f32_16x16x32_bf16(af[mf], bf[nf], acc[mf][nf], 0, 0, 0);
        }
    }
    #pragma unroll
    for (int nf = 0; nf < 4; ++nf) {
        const int col = wn + nf * 16 + lo;
        const float bb = b1[col];
        #pragma unroll
        for (int mf = 0; mf < 2; ++mf)
            #pragma unroll
            for (int j = 0; j < 4; ++j) {
                const int r = n0 + wm + mf * 16 + hi * 4 + j;
                if (r < n) h1[(size_t)r * 128 + col] = f2bf(fmaxf(acc[mf][nf][j] + bb, 0.f));
            }
    }
}

// ---------------- L2: MFMA GEMM 2 (blocks < gemmB)  ||  scan2 (block gemmB) ----------------
__global__ __launch_bounds__(256) void k_lin2(const ushortT* __restrict__ h1,
    const ushortT* __restrict__ w2t, const float* __restrict__ b2,
    ushortT* __restrict__ h2, int n,
    int* __restrict__ bsum, int nb, int gemmB)
{
    if ((int)blockIdx.x >= gemmB) {
        __shared__ int sm[256];
        const int t = threadIdx.x;
        const int v = (t < nb) ? bsum[t] : 0;
        sm[t] = v;
        __syncthreads();
        for (int off = 1; off < 256; off <<= 1) {
            int add = (t >= off) ? sm[t - off] : 0;
            __syncthreads();
            sm[t] += add;
            __syncthreads();
        }
        if (t < nb) bsum[t] = sm[t] - v;
        return;
    }
    __shared__ us8 Ab[64 * 128 / 16];
    __shared__ us8 Bb[64 * 128 / 16];
    char* A = (char*)Ab; char* B = (char*)Bb;
    const int t = threadIdx.x;
    const int w = t >> 6, l = t & 63;
    const int lo = l & 15, hi = l >> 4;
    const int n0 = blockIdx.x * 64;
    const int wm = (w >> 1) * 32, wn = (w & 1) * 32;
    f32x4 acc[2][2];
    #pragma unroll
    for (int mf = 0; mf < 2; ++mf)
        #pragma unroll
        for (int nf = 0; nf < 2; ++nf) acc[mf][nf] = (f32x4){0.f, 0.f, 0.f, 0.f};

    const int arow = t >> 2, ak0 = (t & 3) * 16;
    int agn = n0 + arow; if (agn >= n) agn = n - 1;
    const int asw = (arow & 7) << 4;

    for (int kc = 0; kc < 2; ++kc) {
        __syncthreads();
        {
            const us8 v0 = *(const us8*)&h1[(size_t)agn * 128 + kc * 64 + ak0];
            const us8 v1 = *(const us8*)&h1[(size_t)agn * 128 + kc * 64 + ak0 + 8];
            *(us8*)(A + arow * 128 + ((ak0 * 2) ^ asw)) = v0;
            *(us8*)(A + arow * 128 + ((ak0 * 2 + 16) ^ asw)) = v1;
        }
        #pragma unroll
        for (int i = 0; i < 2; ++i) {
            const int idx = i * 256 + t, br = idx >> 3, bs = idx & 7;
            const us8 v = *(const us8*)&w2t[(size_t)br * 128 + kc * 64 + bs * 8];
            *(us8*)(B + br * 128 + ((bs * 16) ^ ((br & 7) << 4))) = v;
        }
        __syncthreads();
        #pragma unroll
        for (int ks = 0; ks < 2; ++ks) {
            const int koff = ks * 64 + hi * 16;
            bf16x8 af[2], bf[2];
            #pragma unroll
            for (int mf = 0; mf < 2; ++mf) {
                const int r = wm + mf * 16 + lo;
                af[mf] = *(const bf16x8*)(A + r * 128 + (koff ^ ((r & 7) << 4)));
            }
            #pragma unroll
            for (int nf = 0; nf < 2; ++nf) {
                const int r = wn + nf * 16 + lo;
                bf[nf] = *(const bf16x8*)(B + r * 128 + (koff ^ ((r & 7) << 4)));
            }
            #pragma unroll
            for (int mf = 0; mf < 2; ++mf)
                #pragma unroll
                for (int nf = 0; nf < 2; ++nf)
                    acc[mf][nf] = __builtin_amdgcn_mfma_f32_16x16x32_bf16(af[mf], bf[nf], acc[mf][nf], 0, 0, 0);
        }
    }
    #pragma unroll
    for (int nf = 0; nf < 2; ++nf) {
        const int col = wn + nf * 16 + lo;
        const float bb = b2[col];
        #pragma unroll
        for (int mf = 0; mf < 2; ++mf)
            #pragma unroll
            for (int j = 0; j < 4; ++j) {
                const int r = n0 + wm + mf * 16 + hi * 4 + j;
                if (r < n) h2[(size_t)r * 64 + col] = f2bf(fmaxf(acc[mf][nf][j] + bb, 0.f));
            }
    }
}

// ---------------- L3: MFMA GEMM 3 (blocks < gemmB)  ||  scan3 (rest) ----------------
__global__ __launch_bounds__(256) void k_g1feat(const ushortT* __restrict__ h2,
    const ushortT* __restrict__ g1t, const float* __restrict__ attS, const float* __restrict__ attD,
    ushortT* __restrict__ hg1, float* __restrict__ a1s, float* __restrict__ a1d, int n,
    int* __restrict__ offs, int* __restrict__ cursor, const int* __restrict__ bsum, int E, int gemmB)
{
    if ((int)blockIdx.x >= gemmB) {
        const int sb = blockIdx.x - gemmB;
        const int i = sb * 256 + threadIdx.x;
        if (i < n) {
            int o = offs[i] + bsum[i >> 8];
            offs[i] = o;
            cursor[i] = o;
        }
        if (i == 0) offs[n] = E;
        return;
    }
    __shared__ us8 Ab[64 * 128 / 16];
    __shared__ us8 Bb[256 * 128 / 16];
    char* A = (char*)Ab; char* B = (char*)Bb;
    const int t = threadIdx.x;
    const int w = t >> 6, l = t & 63;
    const int lo = l & 15, hi = l >> 4;
    const int n0 = blockIdx.x * 64;
    const int wm = (w >> 1) * 32, wn = (w & 1) * 128;
    f32x4 acc[2][8];
    #pragma unroll
    for (int mf = 0; mf < 2; ++mf)
        #pragma unroll
        for (int nf = 0; nf < 8; ++nf) acc[mf][nf] = (f32x4){0.f, 0.f, 0.f, 0.f};

    {
        const int arow = t >> 2, ak0 = (t & 3) * 16;
        int agn = n0 + arow; if (agn >= n) agn = n - 1;
        const int asw = (arow & 7) << 4;
        const us8 v0 = *(const us8*)&h2[(size_t)agn * 64 + ak0];
        const us8 v1 = *(const us8*)&h2[(size_t)agn * 64 + ak0 + 8];
        *(us8*)(A + arow * 128 + ((ak0 * 2) ^ asw)) = v0;
        *(us8*)(A + arow * 128 + ((ak0 * 2 + 16) ^ asw)) = v1;
    }
    #pragma unroll
    for (int i = 0; i < 8; ++i) {
        const int idx = i * 256 + t, br = idx >> 3, bs = idx & 7;
        const us8 v = *(const us8*)&g1t[(size_t)br * 64 + bs * 8];
        *(us8*)(B + br * 128 + ((bs * 16) ^ ((br & 7) << 4))) = v;
    }
    __syncthreads();
    #pragma unroll
    for (int ks = 0; ks < 2; ++ks) {
        const int koff = ks * 64 + hi * 16;
        bf16x8 af[2];
        #pragma unroll
        for (int mf = 0; mf < 2; ++mf) {
            const int r = wm + mf * 16 + lo;
            af[mf] = *(const bf16x8*)(A + r * 128 + (koff ^ ((r & 7) << 4)));
        }
        #pragma unroll
        for (int nf = 0; nf < 8; ++nf) {
            const int r = wn + nf * 16 + lo;
            const bf16x8 bf = *(const bf16x8*)(B + r * 128 + (koff ^ ((r & 7) << 4)));
            #pragma unroll
            for (int mf = 0; mf < 2; ++mf)
                acc[mf][nf] = __builtin_amdgcn_mfma_f32_16x16x32_bf16(af[mf], bf, acc[mf][nf], 0, 0, 0);
        }
    }
    float sS[8], sD[8];
    #pragma unroll
    for (int nf = 0; nf < 8; ++nf) {
        sS[nf] = attS[wn + nf * 16 + lo];
        sD[nf] = attD[wn + nf * 16 + lo];
    }
    const int hA = wn >> 6, hB = hA + 1;
    #pragma unroll
    for (int mf = 0; mf < 2; ++mf)
        #pragma unroll
        for (int j = 0; j < 4; ++j) {
            const int r = n0 + wm + mf * 16 + hi * 4 + j;
            float pSA = 0.f, pDA = 0.f, pSB = 0.f, pDB = 0.f;
            #pragma unroll
            for (int nf = 0; nf < 4; ++nf) {
                pSA = fmaf(acc[mf][nf][j], sS[nf], pSA);
                pDA = fmaf(acc[mf][nf][j], sD[nf], pDA);
                pSB = fmaf(acc[mf][nf + 4][j], sS[nf + 4], pSB);
                pDB = fmaf(acc[mf][nf + 4][j], sD[nf + 4], pDB);
            }
            #pragma unroll
            for (int off = 1; off < 16; off <<= 1) {
                pSA += __shfl_xor(pSA, off);
                pDA += __shfl_xor(pDA, off);
                pSB += __shfl_xor(pSB, off);
                pDB += __shfl_xor(pDB, off);
            }
            if (r < n) {
                if (lo == 0) {
                    a1s[r * 4 + hA] = pSA; a1s[r * 4 + hB] = pSB;
                    a1d[r * 4 + hA] = pDA; a1d[r * 4 + hB] = pDB;
                }
                #pragma unroll
                for (int nf = 0; nf < 8; ++nf)
                    hg1[(size_t)r * 256 + wn + nf * 16 + lo] = f2bf(acc[mf][nf][j]);
            }
        }
}

// ---------------- MFMA GEMM 4 + inline GraphNorm params: hg2 = elu(norm(out1)) @ g2w ----------------
__global__ __launch_bounds__(256) void k_g2feat(const ushortT* __restrict__ out1,
    const float* __restrict__ colsum, const float* __restrict__ colsq,
    const float* __restrict__ gw, const float* __restrict__ gb, const float* __restrict__ gms,
    const ushortT* __restrict__ g2t, const float* __restrict__ attS, const float* __restrict__ attD,
    ushortT* __restrict__ hg2, float* __restrict__ a2s, float* __restrict__ a2d, int n)
{
    __shared__ us8 Ab[64 * 128 / 16];
    __shared__ us8 Bb[32 * 128 / 16];
    __shared__ float lsc[256], lsh[256];
    char* A = (char*)Ab; char* B = (char*)Bb;
    const int t = threadIdx.x;
    const int w = t >> 6, l = t & 63;
    const int lo = l & 15, hi = l >> 4;
    const int n0 = blockIdx.x * 64;
    const int wm = w * 16;
    {   // inline norm params
        const float invn = 1.f / (float)n;
        const float mean = colsum[t] * invn;
        const float msq = colsq[t] * invn;
        const float ms = gms[t];
        const float var = msq - 2.f * ms * mean * mean + ms * ms * mean * mean;
        const float sc = gw[t] * rsqrtf(var + GEPS);
        lsc[t] = sc;
        lsh[t] = gb[t] - mean * ms * sc;
    }
    f32x4 acc[2];
    acc[0] = (f32x4){0.f, 0.f, 0.f, 0.f};
    acc[1] = (f32x4){0.f, 0.f, 0.f, 0.f};

    const int arow = t >> 2, ak0 = (t & 3) * 16;
    int agn = n0 + arow; if (agn >= n) agn = n - 1;
    const int asw = (arow & 7) << 4;

    for (int kc = 0; kc < 4; ++kc) {
        __syncthreads();
        {
            ushortT tmp[16];
            const us8 v0 = *(const us8*)&out1[(size_t)agn * 256 + kc * 64 + ak0];
            const us8 v1 = *(const us8*)&out1[(size_t)agn * 256 + kc * 64 + ak0 + 8];
            #pragma unroll
            for (int j = 0; j < 8; ++j) {
                float a = bf2f(v0[j]) * lsc[kc * 64 + ak0 + j] + lsh[kc * 64 + ak0 + j];
                float b = bf2f(v1[j]) * lsc[kc * 64 + ak0 + 8 + j] + lsh[kc * 64 + ak0 + 8 + j];
                a = a > 0.f ? a : __expf(a) - 1.f;
                b = b > 0.f ? b : __expf(b) - 1.f;
                tmp[j] = f2bf(a); tmp[8 + j] = f2bf(b);
            }
            *(us8*)(A + arow * 128 + ((ak0 * 2) ^ asw)) = *(us8*)tmp;
            *(us8*)(A + arow * 128 + ((ak0 * 2 + 16) ^ asw)) = *(us8*)(tmp + 8);
        }
        {
            const int br = t >> 3, bs = t & 7;
            const us8 v = *(const us8*)&g2t[(size_t)br * 256 + kc * 64 + bs * 8];
            *(us8*)(B + br * 128 + ((bs * 16) ^ ((br & 7) << 4))) = v;
        }
        __syncthreads();
        #pragma unroll
        for (int ks = 0; ks < 2; ++ks) {
            const int koff = ks * 64 + hi * 16;
            const int ra = wm + lo;
            const bf16x8 af = *(const bf16x8*)(A + ra * 128 + (koff ^ ((ra & 7) << 4)));
            #pragma unroll
            for (int nf = 0; nf < 2; ++nf) {
                const int r = nf * 16 + lo;
                const bf16x8 bf = *(const bf16x8*)(B + r * 128 + (koff ^ ((r & 7) << 4)));
                acc[nf] = __builtin_amdgcn_mfma_f32_16x16x32_bf16(af, bf, acc[nf], 0, 0, 0);
            }
        }
    }
    float sS[2], sD[2];
    sS[0] = attS[lo]; sS[1] = attS[16 + lo];
    sD[0] = attD[lo]; sD[1] = attD[16 + lo];
    #pragma unroll
    for (int j = 0; j < 4; ++j) {
        const int r = n0 + wm + hi * 4 + j;
        float pS = fmaf(acc[0][j], sS[0], acc[1][j] * sS[1]);
        float pD = fmaf(acc[0][j], sD[0], acc[1][j] * sD[1]);
        #pragma unroll
        for (int off = 1; off < 16; off <<= 1) {
            pS += __shfl_xor(pS, off);
            pD += __shfl_xor(pD, off);
        }
        if (r < n) {
            if (lo == 0) { a2s[r] = pS; a2d[r] = pD; }
            hg2[(size_t)r * 32 + lo] = f2bf(acc[0][j]);
            hg2[(size_t)r * 32 + 16 + lo] = f2bf(acc[1][j]);
        }
    }
}

// ---------------- scatter ----------------
__global__ void k_scatter(const int* __restrict__ src, const int* __restrict__ dst,
                          int* __restrict__ cursor, int* __restrict__ csr, int e) {
    int i = blockIdx.x * 256 + threadIdx.x;
    if (i < e) {
        int p = atomicAdd(&cursor[dst[i]], 1);
        csr[p] = src[i];
    }
}

// ---------------- GAT1 alpha precompute: 16-lane group per node, fp32 output ----------------
__global__ __launch_bounds__(256) void k_alpha1(
    const float* __restrict__ a1s, const float* __restrict__ a1d,
    const int* __restrict__ offs, const int* __restrict__ csr,
    float* __restrict__ alphaE, int n)
{
    const int l = threadIdx.x & 15;
    const int d = blockIdx.x * 16 + (threadIdx.x >> 4);
    if (d >= n) return;
    const int start = offs[d], end = offs[d + 1];
    const float4* __restrict__ a1s4 = (const float4*)a1s;
    const float4 adv = ((const float4*)a1d)[d];
    const float ad0 = adv.x, ad1 = adv.y, ad2 = adv.z, ad3 = adv.w;

    float m0 = -1e30f, m1 = -1e30f, m2 = -1e30f, m3 = -1e30f;
    float s0 = 0.f, s1 = 0.f, s2 = 0.f, s3 = 0.f;
    for (int e = start + l; e < end; e += 16) {
        const float4 av = a1s4[csr[e]];
        const float l0 = lrelu(av.x + ad0), l1 = lrelu(av.y + ad1);
        const float l2 = lrelu(av.z + ad2), l3 = lrelu(av.w + ad3);
        float nm;
        nm = fmaxf(m0, l0); s0 = s0 * __expf(m0 - nm) + __expf(l0 - nm); m0 = nm;
        nm = fmaxf(m1, l1); s1 = s1 * __expf(m1 - nm) + __expf(l1 - nm); m1 = nm;
        nm = fmaxf(m2, l2); s2 = s2 * __expf(m2 - nm) + __expf(l2 - nm); m2 = nm;
        nm = fmaxf(m3, l3); s3 = s3 * __expf(m3 - nm) + __expf(l3 - nm); m3 = nm;
    }
    for (int off = 1; off < 16; off <<= 1) {
        float om, os, nm;
        om = __shfl_xor(m0, off, 16); os = __shfl_xor(s0, off, 16);
        nm = fmaxf(m0, om); s0 = s0 * __expf(m0 - nm) + os * __expf(om - nm); m0 = nm;
        om = __shfl_xor(m1, off, 16); os = __shfl_xor(s1, off, 16);
        nm = fmaxf(m1, om); s1 = s1 * __expf(m1 - nm) + os * __expf(om - nm); m1 = nm;
        om = __shfl_xor(m2, off, 16); os = __shfl_xor(s2, off, 16);
        nm = fmaxf(m2, om); s2 = s2 * __expf(m2 - nm) + os * __expf(om - nm); m2 = nm;
        om = __shfl_xor(m3, off, 16); os = __shfl_xor(s3, off, 16);
        nm = fmaxf(m3, om); s3 = s3 * __expf(m3 - nm) + os * __expf(om - nm); m3 = nm;
    }
    const float i0 = 1.f / (s0 + 1e-16f), i1 = 1.f / (s1 + 1e-16f);
    const float i2 = 1.f / (s2 + 1e-16f), i3 = 1.f / (s3 + 1e-16f);
    for (int e = start + l; e < end; e += 16) {
        const float4 av = a1s4[csr[e]];
        float4 o;
        o.x = __expf(lrelu(av.x + ad0) - m0) * i0;
        o.y = __expf(lrelu(av.y + ad1) - m1) * i1;
        o.z = __expf(lrelu(av.z + ad2) - m2) * i2;
        o.w = __expf(lrelu(av.w + ad3) - m3) * i3;
        *(float4*)&alphaE[(size_t)e * 4] = o;
    }
}

// ---------------- GAT1 PV gather: 2 edge-slots x 32 lanes x ushort8 + fused colstat ----------------
__global__ __launch_bounds__(256, 8) void k_pv1(
    const ushortT* __restrict__ hg1, const float* __restrict__ alphaE,
    const int* __restrict__ offs, const int* __restrict__ csr,
    const float* __restrict__ bias, ushortT* __restrict__ out1,
    float* __restrict__ colsum, float* __restrict__ colsq, int n)
{
    __shared__ float scs[4][256], scq[4][256];
    const int tid = threadIdx.x;
    const int lane = tid & 63, w = tid >> 6;
    const int d = blockIdx.x * 4 + w;
    const int cg = lane & 31;
    const int c = cg * 8;
    const int es = lane >> 5;
    const int head = cg >> 3;
    #pragma unroll
    for (int q = 0; q < 4; ++q) { scs[q][tid] = 0.f; scq[q][tid] = 0.f; }
    __syncthreads();

    if (d < n) {
        const int start = offs[d], end = offs[d + 1];
        float acc[8];
        #pragma unroll
        for (int j = 0; j < 8; ++j) acc[j] = 0.f;

        #pragma unroll 4
        for (int e = start + es; e < end; e += 2) {
            const int si = csr[e];
            const float al = alphaE[(size_t)e * 4 + head];
            const us8 hv = *(const us8*)&hg1[(size_t)si * 256 + c];
            #pragma unroll
            for (int j = 0; j < 8; ++j) acc[j] = fmaf(al, bf2f(hv[j]), acc[j]);
        }
        #pragma unroll
        for (int j = 0; j < 8; ++j) acc[j] += __shfl_xor(acc[j], 32);
        if (es == 0) {
            const float4 b0 = *(const float4*)&bias[c];
            const float4 b1 = *(const float4*)&bias[c + 4];
            float v[8];
            v[0] = acc[0] + b0.x; v[1] = acc[1] + b0.y; v[2] = acc[2] + b0.z; v[3] = acc[3] + b0.w;
            v[4] = acc[4] + b1.x; v[5] = acc[5] + b1.y; v[6] = acc[6] + b1.z; v[7] = acc[7] + b1.w;
            us8 o;
            #pragma unroll
            for (int j = 0; j < 8; ++j) o[j] = f2bf(v[j]);
            *(us8*)&out1[(size_t)d * 256 + c] = o;
            #pragma unroll
            for (int j = 0; j < 8; ++j) {
                scs[w][c + j] = v[j];
                scq[w][c + j] = v[j] * v[j];
            }
        }
    }
    __syncthreads();
    const float s4 = scs[0][tid] + scs[1][tid] + scs[2][tid] + scs[3][tid];
    const float q4 = scq[0][tid] + scq[1][tid] + scq[2][tid] + scq[3][tid];
    atomicAdd(&colsum[tid], s4);
    atomicAdd(&colsq[tid], q4);
}

// ---------------- GAT2: fused alpha softmax + PV + bias + log_softmax (32-lane wave per node) ----------------
__global__ __launch_bounds__(256, 8) void k_pv2(
    const ushortT* __restrict__ hg2, const float* __restrict__ a2s, const float* __restrict__ a2d,
    const int* __restrict__ offs, const int* __restrict__ csr,
    const float* __restrict__ bias, float* __restrict__ out, int n)
{
    const int lane = threadIdx.x & 31;
    const int d = blockIdx.x * 8 + (threadIdx.x >> 5);
    if (d >= n) return;
    const int start = offs[d], end = offs[d + 1];
    const float adv = a2d[d];
    // pass 1: softmax stats over this node's edges (32-lane strided)
    float m = -1e30f, s = 0.f;
    for (int e = start + lane; e < end; e += 32) {
        const float lv = lrelu(a2s[csr[e]] + adv);
        const float nm = fmaxf(m, lv);
        s = s * __expf(m - nm) + __expf(lv - nm);
        m = nm;
    }
    for (int off = 1; off < 32; off <<= 1) {
        const float om = __shfl_xor(m, off, 32), os = __shfl_xor(s, off, 32);
        const float nm = fmaxf(m, om);
        s = s * __expf(m - nm) + os * __expf(om - nm);
        m = nm;
    }
    const float inv = 1.f / (s + 1e-16f);
    // pass 2: PV, 2 edge-slots x 16 channel-pair lanes
    const int l = lane & 15, es = lane >> 4;
    const int c = l * 2;
    float acc0 = 0.f, acc1 = 0.f;
    #pragma unroll 4
    for (int e = start + es; e < end; e += 2) {
        const int si = csr[e];
        const float al = __expf(lrelu(a2s[si] + adv) - m) * inv;
        const ushort2 hv = *(const ushort2*)&hg2[(size_t)si * 32 + c];
        acc0 = fmaf(al, bf2f(hv.x), acc0);
        acc1 = fmaf(al, bf2f(hv.y), acc1);
    }
    acc0 += __shfl_xor(acc0, 16, 32);
    acc1 += __shfl_xor(acc1, 16, 32);
    const float v0 = acc0 + bias[c];
    const float v1 = acc1 + bias[c + 1];
    float mx = fmaxf(v0, v1);
    for (int off = 1; off < 16; off <<= 1) mx = fmaxf(mx, __shfl_xor(mx, off, 16));
    float se = __expf(v0 - mx) + __expf(v1 - mx);
    for (int off = 1; off < 16; off <<= 1) se += __shfl_xor(se, off, 16);
    const float ls = __logf(se);
    if (es == 0) {
        float2 o = {v0 - mx - ls, v1 - mx - ls};
        *(float2*)&out[(size_t)d * 32 + c] = o;
    }
}

// ---------------- launcher ----------------
extern "C" void kernel_launch(void* const* d_in, const int* in_sizes, int n_in,
                              void* d_out, int out_size, void* d_ws, size_t ws_size,
                              hipStream_t stream)
{
    const float* x    = (const float*)d_in[0];
    const int*   ei   = (const int*)d_in[1];
    const float* t1w  = (const float*)d_in[2];
    const float* t1b  = (const float*)d_in[3];
    const float* t2w  = (const float*)d_in[4];
    const float* t2b  = (const float*)d_in[5];
    const float* g1w  = (const float*)d_in[6];
    const float* g1as = (const float*)d_in[7];
    const float* g1ad = (const float*)d_in[8];
    const float* g1b  = (const float*)d_in[9];
    const float* gnw  = (const float*)d_in[10];
    const float* gnb  = (const float*)d_in[11];
    const float* gnms = (const float*)d_in[12];
    const float* g2w  = (const float*)d_in[13];
    const float* g2as = (const float*)d_in[14];
    const float* g2ad = (const float*)d_in[15];
    const float* g2b  = (const float*)d_in[16];

    const int N = in_sizes[0] / 256;
    const int E = in_sizes[1] / 2;
    const int* srcA = ei;
    const int* dstA = ei + E;

    char* ws = (char*)d_ws;
    size_t cur = 0;
    auto alloc = [&](size_t bytes) -> char* {
        char* p = ws + cur;
        cur += (bytes + 255) & ~(size_t)255;
        return p;
    };
    ushortT* h1      = (ushortT*)alloc((size_t)N * 128 * 2);
    ushortT* h2      = (ushortT*)alloc((size_t)N * 64 * 2);
    ushortT* hg1     = (ushortT*)alloc((size_t)N * 256 * 2);
    float*   a1s     = (float*)alloc((size_t)N * 4 * 4);
    float*   a1d     = (float*)alloc((size_t)N * 4 * 4);
    ushortT* out1    = (ushortT*)alloc((size_t)N * 256 * 2);
    ushortT* hg2     = (ushortT*)alloc((size_t)N * 32 * 2);
    float*   a2s     = (float*)alloc((size_t)N * 4);
    float*   a2d     = (float*)alloc((size_t)N * 4);
    int*     deg     = (int*)alloc((size_t)(N + 1) * 4);
    int*     offs    = (int*)alloc((size_t)(N + 1) * 4);
    int*     cursor  = (int*)alloc((size_t)N * 4);
    int*     bsum    = (int*)alloc(1024);
    int*     csr     = (int*)alloc((size_t)E * 4);
    float*   alphaE  = (float*)alloc((size_t)E * 4 * 4);
    float*   colsum  = (float*)alloc(1024);
    float*   colsq   = (float*)alloc(1024);
    ushortT* w1t     = (ushortT*)alloc(128 * 256 * 2);
    ushortT* w2t     = (ushortT*)alloc(64 * 128 * 2);
    ushortT* g1t     = (ushortT*)alloc(256 * 64 * 2);
    ushortT* g2t     = (ushortT*)alloc(32 * 256 * 2);

    hipMemsetAsync(deg, 0, (size_t)(N + 1) * 4, stream);
    hipMemsetAsync(colsum, 0, 2048, stream);   // colsum + colsq contiguous

    const int EB  = (E + 255) / 256;
    const int NB  = (N + 255) / 256;
    const int B64 = (N + 63) / 64;
    const int B16 = (N + 15) / 16;
    const int B8  = (N + 7) / 8;
    const int B4  = (N + 3) / 4;

    k_prep_hist<<<128 + EB, 256, 0, stream>>>(t1w, t2w, g1w, g2w, w1t, w2t, g1t, g2t, dstA, deg, E);
    k_lin1<<<B64 + NB, 256, 0, stream>>>(x, w1t, t1b, h1, N, deg, offs, bsum, B64);
    k_lin2<<<B64 + 1, 256, 0, stream>>>(h1, w2t, t2b, h2, N, bsum, NB, B64);
    k_g1feat<<<B64 + NB, 256, 0, stream>>>(h2, g1t, g1as, g1ad, hg1, a1s, a1d, N, offs, cursor, bsum, E, B64);
    k_scatter<<<EB, 256, 0, stream>>>(srcA, dstA, cursor, csr, E);
    k_alpha1<<<B16, 256, 0, stream>>>(a1s, a1d, offs, csr, alphaE, N);
    k_pv1<<<B4, 256, 0, stream>>>(hg1, alphaE, offs, csr, g1b, out1, colsum, colsq, N);
    k_g2feat<<<B64, 256, 0, stream>>>(out1, colsum, colsq, gnw, gnb, gnms, g2t, g2as, g2ad, hg2, a2s, a2d, N);
    k_pv2<<<B8, 256, 0, stream>>>(hg2, a2s, a2d, offs, csr, g2b, (float*)d_out, N);
}

// Round 11
// 289.124 us; speedup vs baseline: 1.7397x; 1.7397x over previous
//
#include <hip/hip_runtime.h>

#define NSLOPE 0.2f
#define GEPS 1e-5f

typedef unsigned short ushortT;
typedef __attribute__((ext_vector_type(8))) unsigned short us8;
typedef __attribute__((ext_vector_type(8))) __bf16 bf16x8;
typedef __attribute__((ext_vector_type(4))) float f32x4;

__device__ __forceinline__ float lrelu(float x) { return x >= 0.f ? x : NSLOPE * x; }
__device__ __forceinline__ ushortT f2bf(float f) {
    unsigned int u = __float_as_uint(f);
    return (ushortT)((u + 0x7fffu + ((u >> 16) & 1u)) >> 16);
}
__device__ __forceinline__ float bf2f(ushortT h) {
    return __uint_as_float((unsigned int)h << 16);
}

// ---------------- L0: weight prep (blocks 0..127)  ||  edge histogram (rest) ----------------
__global__ __launch_bounds__(256) void k_prep_hist(
    const float* __restrict__ w1, const float* __restrict__ w2,
    const float* __restrict__ g1w, const float* __restrict__ g2w,
    ushortT* __restrict__ w1t, ushortT* __restrict__ w2t,
    ushortT* __restrict__ g1t, ushortT* __restrict__ g2t,
    const int* __restrict__ dst, int* __restrict__ deg, int E)
{
    if (blockIdx.x >= 128) {
        const int i = (blockIdx.x - 128) * 256 + threadIdx.x;
        if (i < E) atomicAdd(&deg[dst[i]], 1);
        return;
    }
    const int i = blockIdx.x * 256 + threadIdx.x;
    if (i < 128 * 256) { const int c = i >> 8, k = i & 255; w1t[i] = f2bf(w1[k * 128 + c]); }
    if (i < 64 * 128)  { const int c = i >> 7, k = i & 127; w2t[i] = f2bf(w2[k * 64 + c]); }
    if (i < 256 * 64)  { const int c = i >> 6, k = i & 63;  g1t[i] = f2bf(g1w[k * 256 + c]); }
    if (i < 32 * 256)  { const int c = i >> 8, k = i & 255; g2t[i] = f2bf(g2w[k * 32 + c]); }
}

// ---------------- L1: MFMA GEMM 1 (blocks < gemmB)  ||  scan1 (rest) ----------------
__global__ __launch_bounds__(256) void k_lin1(const float* __restrict__ x,
    const ushortT* __restrict__ w1t, const float* __restrict__ b1,
    ushortT* __restrict__ h1, int n,
    const int* __restrict__ deg, int* __restrict__ offs, int* __restrict__ bsum, int gemmB)
{
    if ((int)blockIdx.x >= gemmB) {
        __shared__ int sm[256];
        const int t = threadIdx.x;
        const int i = (blockIdx.x - gemmB) * 256 + t;
        const int v = (i < n) ? deg[i] : 0;
        sm[t] = v;
        __syncthreads();
        for (int off = 1; off < 256; off <<= 1) {
            int add = (t >= off) ? sm[t - off] : 0;
            __syncthreads();
            sm[t] += add;
            __syncthreads();
        }
        if (i < n) offs[i] = sm[t] - v;
        if (t == 255) bsum[blockIdx.x - gemmB] = sm[255];
        return;
    }
    __shared__ us8 Ab[64 * 128 / 16];
    __shared__ us8 Bb[128 * 128 / 16];
    char* A = (char*)Ab; char* B = (char*)Bb;
    const int t = threadIdx.x;
    const int w = t >> 6, l = t & 63;
    const int lo = l & 15, hi = l >> 4;
    const int n0 = blockIdx.x * 64;
    const int wm = (w >> 1) * 32, wn = (w & 1) * 64;
    f32x4 acc[2][4];
    #pragma unroll
    for (int mf = 0; mf < 2; ++mf)
        #pragma unroll
        for (int nf = 0; nf < 4; ++nf) acc[mf][nf] = (f32x4){0.f, 0.f, 0.f, 0.f};

    const int arow = t >> 2, ak0 = (t & 3) * 16;
    int agn = n0 + arow; if (agn >= n) agn = n - 1;
    const int asw = (arow & 7) << 4;

    for (int kc = 0; kc < 4; ++kc) {
        __syncthreads();
        {
            ushortT tmp[16];
            const float* xp = &x[(size_t)agn * 256 + kc * 64 + ak0];
            #pragma unroll
            for (int j = 0; j < 4; ++j) {
                const float4 v = *(const float4*)(xp + j * 4);
                tmp[j*4+0] = f2bf(v.x); tmp[j*4+1] = f2bf(v.y);
                tmp[j*4+2] = f2bf(v.z); tmp[j*4+3] = f2bf(v.w);
            }
            *(us8*)(A + arow * 128 + ((ak0 * 2) ^ asw)) = *(us8*)tmp;
            *(us8*)(A + arow * 128 + ((ak0 * 2 + 16) ^ asw)) = *(us8*)(tmp + 8);
        }
        #pragma unroll
        for (int i = 0; i < 4; ++i) {
            const int idx = i * 256 + t, br = idx >> 3, bs = idx & 7;
            const us8 v = *(const us8*)&w1t[(size_t)br * 256 + kc * 64 + bs * 8];
            *(us8*)(B + br * 128 + ((bs * 16) ^ ((br & 7) << 4))) = v;
        }
        __syncthreads();
        #pragma unroll
        for (int ks = 0; ks < 2; ++ks) {
            const int koff = ks * 64 + hi * 16;
            bf16x8 af[2], bf[4];
            #pragma unroll
            for (int mf = 0; mf < 2; ++mf) {
                const int r = wm + mf * 16 + lo;
                af[mf] = *(const bf16x8*)(A + r * 128 + (koff ^ ((r & 7) << 4)));
            }
            #pragma unroll
            for (int nf = 0; nf < 4; ++nf) {
                const int r = wn + nf * 16 + lo;
                bf[nf] = *(const bf16x8*)(B + r * 128 + (koff ^ ((r & 7) << 4)));
            }
            #pragma unroll
            for (int mf = 0; mf < 2; ++mf)
                #pragma unroll
                for (int nf = 0; nf < 4; ++nf)
                    acc[mf][nf] = __builtin_amdgcn_mfma_f32_16x16x32_bf16(af[mf], bf[nf], acc[mf][nf], 0, 0, 0);
        }
    }
    #pragma unroll
    for (int nf = 0; nf < 4; ++nf) {
        const int col = wn + nf * 16 + lo;
        const float bb = b1[col];
        #pragma unroll
        for (int mf = 0; mf < 2; ++mf)
            #pragma unroll
            for (int j = 0; j < 4; ++j) {
                const int r = n0 + wm + mf * 16 + hi * 4 + j;
                if (r < n) h1[(size_t)r * 128 + col] = f2bf(fmaxf(acc[mf][nf][j] + bb, 0.f));
            }
    }
}

// ---------------- L2: MFMA GEMM 2 (blocks < gemmB)  ||  scan2 (block gemmB) ----------------
__global__ __launch_bounds__(256) void k_lin2(const ushortT* __restrict__ h1,
    const ushortT* __restrict__ w2t, const float* __restrict__ b2,
    ushortT* __restrict__ h2, int n,
    int* __restrict__ bsum, int nb, int gemmB)
{
    if ((int)blockIdx.x >= gemmB) {
        __shared__ int sm[256];
        const int t = threadIdx.x;
        const int v = (t < nb) ? bsum[t] : 0;
        sm[t] = v;
        __syncthreads();
        for (int off = 1; off < 256; off <<= 1) {
            int add = (t >= off) ? sm[t - off] : 0;
            __syncthreads();
            sm[t] += add;
            __syncthreads();
        }
        if (t < nb) bsum[t] = sm[t] - v;
        return;
    }
    __shared__ us8 Ab[64 * 128 / 16];
    __shared__ us8 Bb[64 * 128 / 16];
    char* A = (char*)Ab; char* B = (char*)Bb;
    const int t = threadIdx.x;
    const int w = t >> 6, l = t & 63;
    const int lo = l & 15, hi = l >> 4;
    const int n0 = blockIdx.x * 64;
    const int wm = (w >> 1) * 32, wn = (w & 1) * 32;
    f32x4 acc[2][2];
    #pragma unroll
    for (int mf = 0; mf < 2; ++mf)
        #pragma unroll
        for (int nf = 0; nf < 2; ++nf) acc[mf][nf] = (f32x4){0.f, 0.f, 0.f, 0.f};

    const int arow = t >> 2, ak0 = (t & 3) * 16;
    int agn = n0 + arow; if (agn >= n) agn = n - 1;
    const int asw = (arow & 7) << 4;

    for (int kc = 0; kc < 2; ++kc) {
        __syncthreads();
        {
            const us8 v0 = *(const us8*)&h1[(size_t)agn * 128 + kc * 64 + ak0];
            const us8 v1 = *(const us8*)&h1[(size_t)agn * 128 + kc * 64 + ak0 + 8];
            *(us8*)(A + arow * 128 + ((ak0 * 2) ^ asw)) = v0;
            *(us8*)(A + arow * 128 + ((ak0 * 2 + 16) ^ asw)) = v1;
        }
        #pragma unroll
        for (int i = 0; i < 2; ++i) {
            const int idx = i * 256 + t, br = idx >> 3, bs = idx & 7;
            const us8 v = *(const us8*)&w2t[(size_t)br * 128 + kc * 64 + bs * 8];
            *(us8*)(B + br * 128 + ((bs * 16) ^ ((br & 7) << 4))) = v;
        }
        __syncthreads();
        #pragma unroll
        for (int ks = 0; ks < 2; ++ks) {
            const int koff = ks * 64 + hi * 16;
            bf16x8 af[2], bf[2];
            #pragma unroll
            for (int mf = 0; mf < 2; ++mf) {
                const int r = wm + mf * 16 + lo;
                af[mf] = *(const bf16x8*)(A + r * 128 + (koff ^ ((r & 7) << 4)));
            }
            #pragma unroll
            for (int nf = 0; nf < 2; ++nf) {
                const int r = wn + nf * 16 + lo;
                bf[nf] = *(const bf16x8*)(B + r * 128 + (koff ^ ((r & 7) << 4)));
            }
            #pragma unroll
            for (int mf = 0; mf < 2; ++mf)
                #pragma unroll
                for (int nf = 0; nf < 2; ++nf)
                    acc[mf][nf] = __builtin_amdgcn_mfma_f32_16x16x32_bf16(af[mf], bf[nf], acc[mf][nf], 0, 0, 0);
        }
    }
    #pragma unroll
    for (int nf = 0; nf < 2; ++nf) {
        const int col = wn + nf * 16 + lo;
        const float bb = b2[col];
        #pragma unroll
        for (int mf = 0; mf < 2; ++mf)
            #pragma unroll
            for (int j = 0; j < 4; ++j) {
                const int r = n0 + wm + mf * 16 + hi * 4 + j;
                if (r < n) h2[(size_t)r * 64 + col] = f2bf(fmaxf(acc[mf][nf][j] + bb, 0.f));
            }
    }
}

// ---------------- L3: MFMA GEMM 3 (blocks < gemmB)  ||  scan3 (rest) ----------------
__global__ __launch_bounds__(256) void k_g1feat(const ushortT* __restrict__ h2,
    const ushortT* __restrict__ g1t, const float* __restrict__ attS, const float* __restrict__ attD,
    ushortT* __restrict__ hg1, float* __restrict__ a1s, float* __restrict__ a1d, int n,
    int* __restrict__ offs, int* __restrict__ cursor, const int* __restrict__ bsum, int E, int gemmB)
{
    if ((int)blockIdx.x >= gemmB) {
        const int sb = blockIdx.x - gemmB;
        const int i = sb * 256 + threadIdx.x;
        if (i < n) {
            int o = offs[i] + bsum[i >> 8];
            offs[i] = o;
            cursor[i] = o;
        }
        if (i == 0) offs[n] = E;
        return;
    }
    __shared__ us8 Ab[64 * 128 / 16];
    __shared__ us8 Bb[256 * 128 / 16];
    char* A = (char*)Ab; char* B = (char*)Bb;
    const int t = threadIdx.x;
    const int w = t >> 6, l = t & 63;
    const int lo = l & 15, hi = l >> 4;
    const int n0 = blockIdx.x * 64;
    const int wm = (w >> 1) * 32, wn = (w & 1) * 128;
    f32x4 acc[2][8];
    #pragma unroll
    for (int mf = 0; mf < 2; ++mf)
        #pragma unroll
        for (int nf = 0; nf < 8; ++nf) acc[mf][nf] = (f32x4){0.f, 0.f, 0.f, 0.f};

    {
        const int arow = t >> 2, ak0 = (t & 3) * 16;
        int agn = n0 + arow; if (agn >= n) agn = n - 1;
        const int asw = (arow & 7) << 4;
        const us8 v0 = *(const us8*)&h2[(size_t)agn * 64 + ak0];
        const us8 v1 = *(const us8*)&h2[(size_t)agn * 64 + ak0 + 8];
        *(us8*)(A + arow * 128 + ((ak0 * 2) ^ asw)) = v0;
        *(us8*)(A + arow * 128 + ((ak0 * 2 + 16) ^ asw)) = v1;
    }
    #pragma unroll
    for (int i = 0; i < 8; ++i) {
        const int idx = i * 256 + t, br = idx >> 3, bs = idx & 7;
        const us8 v = *(const us8*)&g1t[(size_t)br * 64 + bs * 8];
        *(us8*)(B + br * 128 + ((bs * 16) ^ ((br & 7) << 4))) = v;
    }
    __syncthreads();
    #pragma unroll
    for (int ks = 0; ks < 2; ++ks) {
        const int koff = ks * 64 + hi * 16;
        bf16x8 af[2];
        #pragma unroll
        for (int mf = 0; mf < 2; ++mf) {
            const int r = wm + mf * 16 + lo;
            af[mf] = *(const bf16x8*)(A + r * 128 + (koff ^ ((r & 7) << 4)));
        }
        #pragma unroll
        for (int nf = 0; nf < 8; ++nf) {
            const int r = wn + nf * 16 + lo;
            const bf16x8 bf = *(const bf16x8*)(B + r * 128 + (koff ^ ((r & 7) << 4)));
            #pragma unroll
            for (int mf = 0; mf < 2; ++mf)
                acc[mf][nf] = __builtin_amdgcn_mfma_f32_16x16x32_bf16(af[mf], bf, acc[mf][nf], 0, 0, 0);
        }
    }
    float sS[8], sD[8];
    #pragma unroll
    for (int nf = 0; nf < 8; ++nf) {
        sS[nf] = attS[wn + nf * 16 + lo];
        sD[nf] = attD[wn + nf * 16 + lo];
    }
    const int hA = wn >> 6, hB = hA + 1;
    #pragma unroll
    for (int mf = 0; mf < 2; ++mf)
        #pragma unroll
        for (int j = 0; j < 4; ++j) {
            const int r = n0 + wm + mf * 16 + hi * 4 + j;
            float pSA = 0.f, pDA = 0.f, pSB = 0.f, pDB = 0.f;
            #pragma unroll
            for (int nf = 0; nf < 4; ++nf) {
                pSA = fmaf(acc[mf][nf][j], sS[nf], pSA);
                pDA = fmaf(acc[mf][nf][j], sD[nf], pDA);
                pSB = fmaf(acc[mf][nf + 4][j], sS[nf + 4], pSB);
                pDB = fmaf(acc[mf][nf + 4][j], sD[nf + 4], pDB);
            }
            #pragma unroll
            for (int off = 1; off < 16; off <<= 1) {
                pSA += __shfl_xor(pSA, off);
                pDA += __shfl_xor(pDA, off);
                pSB += __shfl_xor(pSB, off);
                pDB += __shfl_xor(pDB, off);
            }
            if (r < n) {
                if (lo == 0) {
                    a1s[r * 4 + hA] = pSA; a1s[r * 4 + hB] = pSB;
                    a1d[r * 4 + hA] = pDA; a1d[r * 4 + hB] = pDB;
                }
                #pragma unroll
                for (int nf = 0; nf < 8; ++nf)
                    hg1[(size_t)r * 256 + wn + nf * 16 + lo] = f2bf(acc[mf][nf][j]);
            }
        }
}

// ---------------- MFMA GEMM 4 + inline GraphNorm params: hg2 = elu(norm(out1)) @ g2w ----------------
__global__ __launch_bounds__(256) void k_g2feat(const ushortT* __restrict__ out1,
    const float* __restrict__ colsum, const float* __restrict__ colsq,
    const float* __restrict__ gw, const float* __restrict__ gb, const float* __restrict__ gms,
    const ushortT* __restrict__ g2t, const float* __restrict__ attS, const float* __restrict__ attD,
    ushortT* __restrict__ hg2, float* __restrict__ a2s, float* __restrict__ a2d, int n)
{
    __shared__ us8 Ab[64 * 128 / 16];
    __shared__ us8 Bb[32 * 128 / 16];
    __shared__ float lsc[256], lsh[256];
    char* A = (char*)Ab; char* B = (char*)Bb;
    const int t = threadIdx.x;
    const int w = t >> 6, l = t & 63;
    const int lo = l & 15, hi = l >> 4;
    const int n0 = blockIdx.x * 64;
    const int wm = w * 16;
    {   // inline norm params
        const float invn = 1.f / (float)n;
        const float mean = colsum[t] * invn;
        const float msq = colsq[t] * invn;
        const float ms = gms[t];
        const float var = msq - 2.f * ms * mean * mean + ms * ms * mean * mean;
        const float sc = gw[t] * rsqrtf(var + GEPS);
        lsc[t] = sc;
        lsh[t] = gb[t] - mean * ms * sc;
    }
    f32x4 acc[2];
    acc[0] = (f32x4){0.f, 0.f, 0.f, 0.f};
    acc[1] = (f32x4){0.f, 0.f, 0.f, 0.f};

    const int arow = t >> 2, ak0 = (t & 3) * 16;
    int agn = n0 + arow; if (agn >= n) agn = n - 1;
    const int asw = (arow & 7) << 4;

    for (int kc = 0; kc < 4; ++kc) {
        __syncthreads();
        {
            ushortT tmp[16];
            const us8 v0 = *(const us8*)&out1[(size_t)agn * 256 + kc * 64 + ak0];
            const us8 v1 = *(const us8*)&out1[(size_t)agn * 256 + kc * 64 + ak0 + 8];
            #pragma unroll
            for (int j = 0; j < 8; ++j) {
                float a = bf2f(v0[j]) * lsc[kc * 64 + ak0 + j] + lsh[kc * 64 + ak0 + j];
                float b = bf2f(v1[j]) * lsc[kc * 64 + ak0 + 8 + j] + lsh[kc * 64 + ak0 + 8 + j];
                a = a > 0.f ? a : __expf(a) - 1.f;
                b = b > 0.f ? b : __expf(b) - 1.f;
                tmp[j] = f2bf(a); tmp[8 + j] = f2bf(b);
            }
            *(us8*)(A + arow * 128 + ((ak0 * 2) ^ asw)) = *(us8*)tmp;
            *(us8*)(A + arow * 128 + ((ak0 * 2 + 16) ^ asw)) = *(us8*)(tmp + 8);
        }
        {
            const int br = t >> 3, bs = t & 7;
            const us8 v = *(const us8*)&g2t[(size_t)br * 256 + kc * 64 + bs * 8];
            *(us8*)(B + br * 128 + ((bs * 16) ^ ((br & 7) << 4))) = v;
        }
        __syncthreads();
        #pragma unroll
        for (int ks = 0; ks < 2; ++ks) {
            const int koff = ks * 64 + hi * 16;
            const int ra = wm + lo;
            const bf16x8 af = *(const bf16x8*)(A + ra * 128 + (koff ^ ((ra & 7) << 4)));
            #pragma unroll
            for (int nf = 0; nf < 2; ++nf) {
                const int r = nf * 16 + lo;
                const bf16x8 bf = *(const bf16x8*)(B + r * 128 + (koff ^ ((r & 7) << 4)));
                acc[nf] = __builtin_amdgcn_mfma_f32_16x16x32_bf16(af, bf, acc[nf], 0, 0, 0);
            }
        }
    }
    float sS[2], sD[2];
    sS[0] = attS[lo]; sS[1] = attS[16 + lo];
    sD[0] = attD[lo]; sD[1] = attD[16 + lo];
    #pragma unroll
    for (int j = 0; j < 4; ++j) {
        const int r = n0 + wm + hi * 4 + j;
        float pS = fmaf(acc[0][j], sS[0], acc[1][j] * sS[1]);
        float pD = fmaf(acc[0][j], sD[0], acc[1][j] * sD[1]);
        #pragma unroll
        for (int off = 1; off < 16; off <<= 1) {
            pS += __shfl_xor(pS, off);
            pD += __shfl_xor(pD, off);
        }
        if (r < n) {
            if (lo == 0) { a2s[r] = pS; a2d[r] = pD; }
            hg2[(size_t)r * 32 + lo] = f2bf(acc[0][j]);
            hg2[(size_t)r * 32 + 16 + lo] = f2bf(acc[1][j]);
        }
    }
}

// ---------------- scatter ----------------
__global__ void k_scatter(const int* __restrict__ src, const int* __restrict__ dst,
                          int* __restrict__ cursor, int* __restrict__ csr, int e) {
    int i = blockIdx.x * 256 + threadIdx.x;
    if (i < e) {
        int p = atomicAdd(&cursor[dst[i]], 1);
        csr[p] = src[i];
    }
}

// ---------------- GAT1 alpha precompute: 16-lane group per node, fp32 output ----------------
__global__ __launch_bounds__(256) void k_alpha1(
    const float* __restrict__ a1s, const float* __restrict__ a1d,
    const int* __restrict__ offs, const int* __restrict__ csr,
    float* __restrict__ alphaE, int n)
{
    const int l = threadIdx.x & 15;
    const int d = blockIdx.x * 16 + (threadIdx.x >> 4);
    if (d >= n) return;
    const int start = offs[d], end = offs[d + 1];
    const float4* __restrict__ a1s4 = (const float4*)a1s;
    const float4 adv = ((const float4*)a1d)[d];
    const float ad0 = adv.x, ad1 = adv.y, ad2 = adv.z, ad3 = adv.w;

    float m0 = -1e30f, m1 = -1e30f, m2 = -1e30f, m3 = -1e30f;
    float s0 = 0.f, s1 = 0.f, s2 = 0.f, s3 = 0.f;
    for (int e = start + l; e < end; e += 16) {
        const float4 av = a1s4[csr[e]];
        const float l0 = lrelu(av.x + ad0), l1 = lrelu(av.y + ad1);
        const float l2 = lrelu(av.z + ad2), l3 = lrelu(av.w + ad3);
        float nm;
        nm = fmaxf(m0, l0); s0 = s0 * __expf(m0 - nm) + __expf(l0 - nm); m0 = nm;
        nm = fmaxf(m1, l1); s1 = s1 * __expf(m1 - nm) + __expf(l1 - nm); m1 = nm;
        nm = fmaxf(m2, l2); s2 = s2 * __expf(m2 - nm) + __expf(l2 - nm); m2 = nm;
        nm = fmaxf(m3, l3); s3 = s3 * __expf(m3 - nm) + __expf(l3 - nm); m3 = nm;
    }
    for (int off = 1; off < 16; off <<= 1) {
        float om, os, nm;
        om = __shfl_xor(m0, off, 16); os = __shfl_xor(s0, off, 16);
        nm = fmaxf(m0, om); s0 = s0 * __expf(m0 - nm) + os * __expf(om - nm); m0 = nm;
        om = __shfl_xor(m1, off, 16); os = __shfl_xor(s1, off, 16);
        nm = fmaxf(m1, om); s1 = s1 * __expf(m1 - nm) + os * __expf(om - nm); m1 = nm;
        om = __shfl_xor(m2, off, 16); os = __shfl_xor(s2, off, 16);
        nm = fmaxf(m2, om); s2 = s2 * __expf(m2 - nm) + os * __expf(om - nm); m2 = nm;
        om = __shfl_xor(m3, off, 16); os = __shfl_xor(s3, off, 16);
        nm = fmaxf(m3, om); s3 = s3 * __expf(m3 - nm) + os * __expf(om - nm); m3 = nm;
    }
    const float i0 = 1.f / (s0 + 1e-16f), i1 = 1.f / (s1 + 1e-16f);
    const float i2 = 1.f / (s2 + 1e-16f), i3 = 1.f / (s3 + 1e-16f);
    for (int e = start + l; e < end; e += 16) {
        const float4 av = a1s4[csr[e]];
        float4 o;
        o.x = __expf(lrelu(av.x + ad0) - m0) * i0;
        o.y = __expf(lrelu(av.y + ad1) - m1) * i1;
        o.z = __expf(lrelu(av.z + ad2) - m2) * i2;
        o.w = __expf(lrelu(av.w + ad3) - m3) * i3;
        *(float4*)&alphaE[(size_t)e * 4] = o;
    }
}

// ---------------- GAT1 PV gather: 2 edge-slots x 32 lanes x ushort8 (R7 proven form) ----------------
__global__ __launch_bounds__(256, 8) void k_pv1(
    const ushortT* __restrict__ hg1, const float* __restrict__ alphaE,
    const int* __restrict__ offs, const int* __restrict__ csr,
    const float* __restrict__ bias, ushortT* __restrict__ out1, int n)
{
    const int lane = threadIdx.x & 63;
    const int d = blockIdx.x * 4 + (threadIdx.x >> 6);
    if (d >= n) return;
    const int start = offs[d], end = offs[d + 1];
    const int cg = lane & 31;
    const int c = cg * 8;
    const int es = lane >> 5;
    const int head = cg >> 3;
    float acc[8];
    #pragma unroll
    for (int j = 0; j < 8; ++j) acc[j] = 0.f;

    #pragma unroll 4
    for (int e = start + es; e < end; e += 2) {
        const int si = csr[e];
        const float al = alphaE[(size_t)e * 4 + head];
        const us8 hv = *(const us8*)&hg1[(size_t)si * 256 + c];
        #pragma unroll
        for (int j = 0; j < 8; ++j) acc[j] = fmaf(al, bf2f(hv[j]), acc[j]);
    }
    #pragma unroll
    for (int j = 0; j < 8; ++j) acc[j] += __shfl_xor(acc[j], 32);
    if (es == 0) {
        const float4 b0 = *(const float4*)&bias[c];
        const float4 b1 = *(const float4*)&bias[c + 4];
        us8 o;
        o[0] = f2bf(acc[0] + b0.x); o[1] = f2bf(acc[1] + b0.y);
        o[2] = f2bf(acc[2] + b0.z); o[3] = f2bf(acc[3] + b0.w);
        o[4] = f2bf(acc[4] + b1.x); o[5] = f2bf(acc[5] + b1.y);
        o[6] = f2bf(acc[6] + b1.z); o[7] = f2bf(acc[7] + b1.w);
        *(us8*)&out1[(size_t)d * 256 + c] = o;
    }
}

// ---------------- GraphNorm column stats (bf16 input) ----------------
__global__ __launch_bounds__(256) void k_colstat(const ushortT* __restrict__ out1,
    float* __restrict__ colsum, float* __restrict__ colsq, int n)
{
    const int t = threadIdx.x;
    float s = 0.f, q = 0.f;
    for (int r = blockIdx.x; r < n; r += gridDim.x) {
        const float v = bf2f(out1[(size_t)r * 256 + t]);
        s += v;
        q += v * v;
    }
    atomicAdd(&colsum[t], s);
    atomicAdd(&colsq[t], q);
}

// ---------------- GAT2: fused alpha softmax + PV + bias + log_softmax (32-lane wave per node) ----------------
__global__ __launch_bounds__(256, 8) void k_pv2(
    const ushortT* __restrict__ hg2, const float* __restrict__ a2s, const float* __restrict__ a2d,
    const int* __restrict__ offs, const int* __restrict__ csr,
    const float* __restrict__ bias, float* __restrict__ out, int n)
{
    const int lane = threadIdx.x & 31;
    const int d = blockIdx.x * 8 + (threadIdx.x >> 5);
    if (d >= n) return;
    const int start = offs[d], end = offs[d + 1];
    const float adv = a2d[d];
    // pass 1: softmax stats over this node's edges (32-lane strided)
    float m = -1e30f, s = 0.f;
    for (int e = start + lane; e < end; e += 32) {
        const float lv = lrelu(a2s[csr[e]] + adv);
        const float nm = fmaxf(m, lv);
        s = s * __expf(m - nm) + __expf(lv - nm);
        m = nm;
    }
    for (int off = 1; off < 32; off <<= 1) {
        const float om = __shfl_xor(m, off, 32), os = __shfl_xor(s, off, 32);
        const float nm = fmaxf(m, om);
        s = s * __expf(m - nm) + os * __expf(om - nm);
        m = nm;
    }
    const float inv = 1.f / (s + 1e-16f);
    // pass 2: PV, 2 edge-slots x 16 channel-pair lanes
    const int l = lane & 15, es = lane >> 4;
    const int c = l * 2;
    float acc0 = 0.f, acc1 = 0.f;
    #pragma unroll 4
    for (int e = start + es; e < end; e += 2) {
        const int si = csr[e];
        const float al = __expf(lrelu(a2s[si] + adv) - m) * inv;
        const ushort2 hv = *(const ushort2*)&hg2[(size_t)si * 32 + c];
        acc0 = fmaf(al, bf2f(hv.x), acc0);
        acc1 = fmaf(al, bf2f(hv.y), acc1);
    }
    acc0 += __shfl_xor(acc0, 16, 32);
    acc1 += __shfl_xor(acc1, 16, 32);
    const float v0 = acc0 + bias[c];
    const float v1 = acc1 + bias[c + 1];
    float mx = fmaxf(v0, v1);
    for (int off = 1; off < 16; off <<= 1) mx = fmaxf(mx, __shfl_xor(mx, off, 16));
    float se = __expf(v0 - mx) + __expf(v1 - mx);
    for (int off = 1; off < 16; off <<= 1) se += __shfl_xor(se, off, 16);
    const float ls = __logf(se);
    if (es == 0) {
        float2 o = {v0 - mx - ls, v1 - mx - ls};
        *(float2*)&out[(size_t)d * 32 + c] = o;
    }
}

// ---------------- launcher ----------------
extern "C" void kernel_launch(void* const* d_in, const int* in_sizes, int n_in,
                              void* d_out, int out_size, void* d_ws, size_t ws_size,
                              hipStream_t stream)
{
    const float* x    = (const float*)d_in[0];
    const int*   ei   = (const int*)d_in[1];
    const float* t1w  = (const float*)d_in[2];
    const float* t1b  = (const float*)d_in[3];
    const float* t2w  = (const float*)d_in[4];
    const float* t2b  = (const float*)d_in[5];
    const float* g1w  = (const float*)d_in[6];
    const float* g1as = (const float*)d_in[7];
    const float* g1ad = (const float*)d_in[8];
    const float* g1b  = (const float*)d_in[9];
    const float* gnw  = (const float*)d_in[10];
    const float* gnb  = (const float*)d_in[11];
    const float* gnms = (const float*)d_in[12];
    const float* g2w  = (const float*)d_in[13];
    const float* g2as = (const float*)d_in[14];
    const float* g2ad = (const float*)d_in[15];
    const float* g2b  = (const float*)d_in[16];

    const int N = in_sizes[0] / 256;
    const int E = in_sizes[1] / 2;
    const int* srcA = ei;
    const int* dstA = ei + E;

    char* ws = (char*)d_ws;
    size_t cur = 0;
    auto alloc = [&](size_t bytes) -> char* {
        char* p = ws + cur;
        cur += (bytes + 255) & ~(size_t)255;
        return p;
    };
    ushortT* h1      = (ushortT*)alloc((size_t)N * 128 * 2);
    ushortT* h2      = (ushortT*)alloc((size_t)N * 64 * 2);
    ushortT* hg1     = (ushortT*)alloc((size_t)N * 256 * 2);
    float*   a1s     = (float*)alloc((size_t)N * 4 * 4);
    float*   a1d     = (float*)alloc((size_t)N * 4 * 4);
    ushortT* out1    = (ushortT*)alloc((size_t)N * 256 * 2);
    ushortT* hg2     = (ushortT*)alloc((size_t)N * 32 * 2);
    float*   a2s     = (float*)alloc((size_t)N * 4);
    float*   a2d     = (float*)alloc((size_t)N * 4);
    int*     deg     = (int*)alloc((size_t)(N + 1) * 4);
    int*     offs    = (int*)alloc((size_t)(N + 1) * 4);
    int*     cursor  = (int*)alloc((size_t)N * 4);
    int*     bsum    = (int*)alloc(1024);
    int*     csr     = (int*)alloc((size_t)E * 4);
    float*   alphaE  = (float*)alloc((size_t)E * 4 * 4);
    float*   colsum  = (float*)alloc(1024);
    float*   colsq   = (float*)alloc(1024);
    ushortT* w1t     = (ushortT*)alloc(128 * 256 * 2);
    ushortT* w2t     = (ushortT*)alloc(64 * 128 * 2);
    ushortT* g1t     = (ushortT*)alloc(256 * 64 * 2);
    ushortT* g2t     = (ushortT*)alloc(32 * 256 * 2);

    hipMemsetAsync(deg, 0, (size_t)(N + 1) * 4, stream);
    hipMemsetAsync(colsum, 0, 2048, stream);   // colsum + colsq contiguous

    const int EB  = (E + 255) / 256;
    const int NB  = (N + 255) / 256;
    const int B64 = (N + 63) / 64;
    const int B16 = (N + 15) / 16;
    const int B8  = (N + 7) / 8;
    const int B4  = (N + 3) / 4;

    k_prep_hist<<<128 + EB, 256, 0, stream>>>(t1w, t2w, g1w, g2w, w1t, w2t, g1t, g2t, dstA, deg, E);
    k_lin1<<<B64 + NB, 256, 0, stream>>>(x, w1t, t1b, h1, N, deg, offs, bsum, B64);
    k_lin2<<<B64 + 1, 256, 0, stream>>>(h1, w2t, t2b, h2, N, bsum, NB, B64);
    k_g1feat<<<B64 + NB, 256, 0, stream>>>(h2, g1t, g1as, g1ad, hg1, a1s, a1d, N, offs, cursor, bsum, E, B64);
    k_scatter<<<EB, 256, 0, stream>>>(srcA, dstA, cursor, csr, E);
    k_alpha1<<<B16, 256, 0, stream>>>(a1s, a1d, offs, csr, alphaE, N);
    k_pv1<<<B4, 256, 0, stream>>>(hg1, alphaE, offs, csr, g1b, out1, N);
    k_colstat<<<256, 256, 0, stream>>>(out1, colsum, colsq, N);
    k_g2feat<<<B64, 256, 0, stream>>>(out1, colsum, colsq, gnw, gnb, gnms, g2t, g2as, g2ad, hg2, a2s, a2d, N);
    k_pv2<<<B8, 256, 0, stream>>>(hg2, a2s, a2d, offs, csr, g2b, (float*)d_out, N);
}